// Round 1
// baseline (139.313 us; speedup 1.0000x reference)
//
#include <hip/hip_runtime.h>
#include <math.h>

#define B_  32
#define C_  256
#define H_  56
#define W_  56
#define CG_ 64
#define NG_ 4
#define P_  7
#define N_  49
#define PLANE_ (H_*W_)
#define EPS_ 1e-5f

__device__ __forceinline__ float sig_(float v) { return 1.0f / (1.0f + expf(-v)); }

// ---------------- K1: row & col means per (b,c) plane ----------------
__global__ __launch_bounds__(256) void k1_means(const float* __restrict__ x,
                                                float* __restrict__ xh,
                                                float* __restrict__ xw) {
  __shared__ float pl[PLANE_];
  const int bc = blockIdx.x;
  const int t  = threadIdx.x;
  const float4* src = (const float4*)(x + (size_t)bc * PLANE_);
  float4* dst = (float4*)pl;
  for (int i = t; i < PLANE_ / 4; i += 256) dst[i] = src[i];
  __syncthreads();
  if (t < H_) {
    float s = 0.f;
    #pragma unroll
    for (int w = 0; w < W_; ++w) s += pl[t * W_ + w];
    xh[(size_t)bc * H_ + t] = s * (1.0f / W_);
  } else if (t >= 64 && t < 64 + W_) {
    const int w = t - 64;
    float s = 0.f;
    #pragma unroll
    for (int h = 0; h < H_; ++h) s += pl[h * W_ + w];
    xw[(size_t)bc * W_ + w] = s * (1.0f / H_);
  }
}

// ------- K2: depthwise 1D conv (k = 3+2g) + GroupNorm(4) + sigmoid, in-place -------
// grid: (NG_, B_), block 256. buf layout (B, C, 56); slab = 64 ch x 56.
__global__ __launch_bounds__(256) void k2_convgn(float* __restrict__ buf,
    const float* __restrict__ w0, const float* __restrict__ w1,
    const float* __restrict__ w2, const float* __restrict__ w3,
    const float* __restrict__ gw, const float* __restrict__ gb) {
  __shared__ float sin_[CG_ * H_];
  __shared__ float sconv[CG_ * H_];
  __shared__ float redS[4], redQ[4];
  __shared__ float sMu, sRs;
  const int g = blockIdx.x, b = blockIdx.y, t = threadIdx.x;
  const size_t base = ((size_t)b * C_ + (size_t)g * CG_) * H_;
  const float* wt = (g == 0) ? w0 : (g == 1) ? w1 : (g == 2) ? w2 : w3;
  const int k = 3 + 2 * g, pad = k / 2;

  for (int i = t; i < CG_ * H_; i += 256) sin_[i] = buf[base + i];
  __syncthreads();

  float lsum = 0.f, lsq = 0.f;
  for (int i = t; i < CG_ * H_; i += 256) {
    const int cc = i / H_, l = i % H_;
    float s = 0.f;
    for (int j = 0; j < k; ++j) {
      const int ll = l + j - pad;
      if (ll >= 0 && ll < H_) s += sin_[cc * H_ + ll] * wt[cc * k + j];
    }
    sconv[i] = s;
    lsum += s; lsq += s * s;
  }
  #pragma unroll
  for (int m = 32; m >= 1; m >>= 1) { lsum += __shfl_xor(lsum, m); lsq += __shfl_xor(lsq, m); }
  const int wid = t >> 6;
  if ((t & 63) == 0) { redS[wid] = lsum; redQ[wid] = lsq; }
  __syncthreads();
  if (t == 0) {
    const float S = redS[0] + redS[1] + redS[2] + redS[3];
    const float Q = redQ[0] + redQ[1] + redQ[2] + redQ[3];
    const float mu = S / (float)(CG_ * H_);
    const float var = Q / (float)(CG_ * H_) - mu * mu;
    sMu = mu; sRs = rsqrtf(var + EPS_);
  }
  __syncthreads();
  const float mu = sMu, rs = sRs;
  for (int i = t; i < CG_ * H_; i += 256) {
    const int cc = i / H_;
    const int c = g * CG_ + cc;
    const float v = (sconv[i] - mu) * rs * gw[c] + gb[c];
    buf[base + i] = sig_(v);
  }
}

// ---------------- K3: 8x8 block pool of x*Ah*Aw -> xp (B,C,49) ----------------
__global__ __launch_bounds__(256) void k3_pool(const float* __restrict__ x,
    const float* __restrict__ Ah, const float* __restrict__ Aw,
    float* __restrict__ xp) {
  __shared__ float ah[H_], aw[W_];
  __shared__ float part[H_ * P_];   // [h][pw]
  const int bc = blockIdx.x, t = threadIdx.x;
  if (t < H_) ah[t] = Ah[(size_t)bc * H_ + t];
  else if (t >= 64 && t < 64 + W_) aw[t - 64] = Aw[(size_t)bc * W_ + (t - 64)];
  __syncthreads();
  const float4* xx = (const float4*)(x + (size_t)bc * PLANE_);
  for (int i = t; i < H_ * P_; i += 256) {
    const int h = i / P_, pw = i % P_;
    const float4 a = xx[h * 14 + 2 * pw];
    const float4 b = xx[h * 14 + 2 * pw + 1];
    const int w0 = 8 * pw;
    float s = a.x * aw[w0]     + a.y * aw[w0 + 1] + a.z * aw[w0 + 2] + a.w * aw[w0 + 3]
            + b.x * aw[w0 + 4] + b.y * aw[w0 + 5] + b.z * aw[w0 + 6] + b.w * aw[w0 + 7];
    part[i] = s * ah[h];
  }
  __syncthreads();
  if (t < N_) {
    const int ph = t / P_, pw = t % P_;
    float s = 0.f;
    #pragma unroll
    for (int r = 0; r < 8; ++r) s += part[(8 * ph + r) * P_ + pw];
    xp[(size_t)bc * N_ + t] = s * (1.0f / 64.0f);
  }
}

// ------- K4: GN(1 group) + channel attention -> Mc (B,C). grid (8, B_), block 256 -------
__global__ __launch_bounds__(256) void k4_attn(const float* __restrict__ xp,
    const float* __restrict__ gw, const float* __restrict__ gb,
    const float* __restrict__ wq, const float* __restrict__ wk, const float* __restrict__ wv,
    float* __restrict__ Mc) {
  __shared__ float xn[C_ * N_];   // 12544 floats
  __shared__ float vbar[C_];
  __shared__ float swk[C_];
  __shared__ float redS[4], redQ[4];
  __shared__ float sMu, sRs;
  const int chunk = blockIdx.x, b = blockIdx.y, t = threadIdx.x;
  const float* src = xp + (size_t)b * C_ * N_;

  float lsum = 0.f, lsq = 0.f;
  for (int i = t; i < C_ * N_; i += 256) {
    const float v = src[i];
    xn[i] = v; lsum += v; lsq += v * v;
  }
  swk[t] = wk[t];
  #pragma unroll
  for (int m = 32; m >= 1; m >>= 1) { lsum += __shfl_xor(lsum, m); lsq += __shfl_xor(lsq, m); }
  const int wid = t >> 6;
  if ((t & 63) == 0) { redS[wid] = lsum; redQ[wid] = lsq; }
  __syncthreads();
  if (t == 0) {
    const float S = redS[0] + redS[1] + redS[2] + redS[3];
    const float Q = redQ[0] + redQ[1] + redQ[2] + redQ[3];
    const float mu = S / (float)(C_ * N_);
    const float var = Q / (float)(C_ * N_) - mu * mu;
    sMu = mu; sRs = rsqrtf(var + EPS_);
  }
  __syncthreads();
  const float mu = sMu, rs = sRs;
  for (int i = t; i < C_ * N_; i += 256) {
    const int c = i / N_;
    xn[i] = (xn[i] - mu) * rs * gw[c] + gb[c];
  }
  __syncthreads();
  {   // vbar[d] = wv[d] * mean_n xn[d,n]
    float s = 0.f;
    #pragma unroll
    for (int n = 0; n < N_; ++n) s += xn[t * N_ + n];
    vbar[t] = wv[t] * s * (1.0f / N_);
  }
  __syncthreads();

  const int r = t >> 3, q8 = t & 7;     // 32 rows x 8 collaborators
  const int c = chunk * 32 + r;
  const float qscale = wq[c] * (1.0f / 7.0f);   // 1/sqrt(49)

  float qrow[N_];
  #pragma unroll
  for (int n = 0; n < N_; ++n) qrow[n] = xn[c * N_ + n];

  float s[32];
  #pragma unroll
  for (int dd = 0; dd < 32; ++dd) {
    const int d = q8 + 8 * dd;          // interleaved -> conflict-free LDS banks
    const float* kb = &xn[d * N_];
    float dot = 0.f;
    #pragma unroll
    for (int n = 0; n < N_; ++n) dot += qrow[n] * kb[n];
    s[dd] = dot * qscale * swk[d];
  }
  float mx = -INFINITY;
  #pragma unroll
  for (int dd = 0; dd < 32; ++dd) mx = fmaxf(mx, s[dd]);
  #pragma unroll
  for (int msk = 1; msk < 8; msk <<= 1) mx = fmaxf(mx, __shfl_xor(mx, msk));
  float esum = 0.f, acc = 0.f;
  #pragma unroll
  for (int dd = 0; dd < 32; ++dd) {
    const float e = expf(s[dd] - mx);
    esum += e;
    acc += e * vbar[q8 + 8 * dd];
  }
  #pragma unroll
  for (int msk = 1; msk < 8; msk <<= 1) { esum += __shfl_xor(esum, msk); acc += __shfl_xor(acc, msk); }
  if (q8 == 0) Mc[(size_t)b * C_ + c] = sig_(acc / esum);
}

// ---------------- K5: out = x * Ah * Aw * Mc ----------------
__global__ __launch_bounds__(256) void k5_out(const float* __restrict__ x,
    const float* __restrict__ Ah, const float* __restrict__ Aw,
    const float* __restrict__ Mc, float* __restrict__ out) {
  __shared__ float ah[H_], aw[W_];
  __shared__ float smc;
  const int bc = blockIdx.x, t = threadIdx.x;
  if (t < H_) ah[t] = Ah[(size_t)bc * H_ + t];
  else if (t >= 64 && t < 64 + W_) aw[t - 64] = Aw[(size_t)bc * W_ + (t - 64)];
  if (t == 128) smc = Mc[bc];
  __syncthreads();
  const float4* xx = (const float4*)(x + (size_t)bc * PLANE_);
  float4* oo = (float4*)(out + (size_t)bc * PLANE_);
  const float mc = smc;
  for (int i = t; i < PLANE_ / 4; i += 256) {
    const int h = i / 14, w0 = (i % 14) * 4;
    float4 v = xx[i];
    const float a = ah[h] * mc;
    v.x *= a * aw[w0];
    v.y *= a * aw[w0 + 1];
    v.z *= a * aw[w0 + 2];
    v.w *= a * aw[w0 + 3];
    oo[i] = v;
  }
}

extern "C" void kernel_launch(void* const* d_in, const int* in_sizes, int n_in,
                              void* d_out, int out_size, void* d_ws, size_t ws_size,
                              hipStream_t stream) {
  // setup_inputs() dict order: x, dwh0, dww0, dwh1, dww1, dwh2, dww2, dwh3, dww3,
  // gnh_w, gnh_b, gnw_w, gnw_b, gn1_w, gn1_b, wq, wk, wv
  const float* x     = (const float*)d_in[0];
  const float* dwh0  = (const float*)d_in[1];
  const float* dww0  = (const float*)d_in[2];
  const float* dwh1  = (const float*)d_in[3];
  const float* dww1  = (const float*)d_in[4];
  const float* dwh2  = (const float*)d_in[5];
  const float* dww2  = (const float*)d_in[6];
  const float* dwh3  = (const float*)d_in[7];
  const float* dww3  = (const float*)d_in[8];
  const float* gnh_w = (const float*)d_in[9];
  const float* gnh_b = (const float*)d_in[10];
  const float* gnw_w = (const float*)d_in[11];
  const float* gnw_b = (const float*)d_in[12];
  const float* gn1_w = (const float*)d_in[13];
  const float* gn1_b = (const float*)d_in[14];
  const float* wq    = (const float*)d_in[15];
  const float* wk    = (const float*)d_in[16];
  const float* wv    = (const float*)d_in[17];
  float* out = (float*)d_out;

  float* ws   = (float*)d_ws;
  float* bufh = ws;                                   // (B,C,56): x_h then Ah in-place
  float* bufw = bufh + (size_t)B_ * C_ * H_;          // (B,C,56): x_w then Aw in-place
  float* xp   = bufw + (size_t)B_ * C_ * W_;          // (B,C,49)
  float* Mc   = xp + (size_t)B_ * C_ * N_;            // (B,C)

  const int nbc = B_ * C_;
  k1_means<<<nbc, 256, 0, stream>>>(x, bufh, bufw);
  k2_convgn<<<dim3(NG_, B_), 256, 0, stream>>>(bufh, dwh0, dwh1, dwh2, dwh3, gnh_w, gnh_b);
  k2_convgn<<<dim3(NG_, B_), 256, 0, stream>>>(bufw, dww0, dww1, dww2, dww3, gnw_w, gnw_b);
  k3_pool<<<nbc, 256, 0, stream>>>(x, bufh, bufw, xp);
  k4_attn<<<dim3(8, B_), 256, 0, stream>>>(xp, gn1_w, gn1_b, wq, wk, wv, Mc);
  k5_out<<<nbc, 256, 0, stream>>>(x, bufh, bufw, Mc, out);
}

// Round 3
// 118.416 us; speedup vs baseline: 1.1765x; 1.1765x over previous
//
#include <hip/hip_runtime.h>
#include <math.h>

#define B_  32
#define C_  256
#define H_  56
#define W_  56
#define CG_ 64
#define NG_ 4
#define P_  7
#define N_  49
#define PLANE_ (H_*W_)
#define EPS_ 1e-5f

typedef float f4v __attribute__((ext_vector_type(4)));

__device__ __forceinline__ float sig_(float v) { return 1.0f / (1.0f + expf(-v)); }

// ---------------- K1: row & col means per (b,c) plane ----------------
__global__ __launch_bounds__(256) void k1_means(const float* __restrict__ x,
                                                float* __restrict__ xh,
                                                float* __restrict__ xw) {
  __shared__ __align__(16) float pl[PLANE_];
  const int bc = blockIdx.x;
  const int t  = threadIdx.x;
  const f4v* src = (const f4v*)(x + (size_t)bc * PLANE_);
  f4v* dst = (f4v*)pl;
  for (int i = t; i < PLANE_ / 4; i += 256) dst[i] = src[i];   // 784 f4v
  __syncthreads();
  if (t < H_) {
    float s = 0.f;
    #pragma unroll
    for (int w = 0; w < W_; ++w) s += pl[t * W_ + w];
    xh[(size_t)bc * H_ + t] = s * (1.0f / W_);
  } else if (t >= 64 && t < 64 + W_) {
    const int w = t - 64;
    float s = 0.f;
    #pragma unroll
    for (int h = 0; h < H_; ++h) s += pl[h * W_ + w];
    xw[(size_t)bc * W_ + w] = s * (1.0f / H_);
  }
}

// ------- K2: depthwise 1D conv (k = 3+2g) + GroupNorm(4) + sigmoid, in-place -------
// grid: (NG_, B_, 2) — z selects the H-buffer or W-buffer problem. block 256.
__global__ __launch_bounds__(256) void k2_convgn(float* __restrict__ bufh, float* __restrict__ bufw,
    const float* __restrict__ h0, const float* __restrict__ h1,
    const float* __restrict__ h2, const float* __restrict__ h3,
    const float* __restrict__ w0, const float* __restrict__ w1,
    const float* __restrict__ w2, const float* __restrict__ w3,
    const float* __restrict__ gnh_w, const float* __restrict__ gnh_b,
    const float* __restrict__ gnw_w, const float* __restrict__ gnw_b) {
  __shared__ float sin_[CG_ * H_];
  __shared__ float sconv[CG_ * H_];
  __shared__ float redS[4], redQ[4];
  __shared__ float sMu, sRs;
  const int g = blockIdx.x, b = blockIdx.y, zz = blockIdx.z, t = threadIdx.x;
  float* buf = zz ? bufw : bufh;
  const float* wt = zz ? ((g == 0) ? w0 : (g == 1) ? w1 : (g == 2) ? w2 : w3)
                       : ((g == 0) ? h0 : (g == 1) ? h1 : (g == 2) ? h2 : h3);
  const float* gw = zz ? gnw_w : gnh_w;
  const float* gb = zz ? gnw_b : gnh_b;
  const size_t base = ((size_t)b * C_ + (size_t)g * CG_) * H_;
  const int k = 3 + 2 * g, pad = k / 2;

  for (int i = t; i < CG_ * H_; i += 256) sin_[i] = buf[base + i];
  __syncthreads();

  float lsum = 0.f, lsq = 0.f;
  for (int i = t; i < CG_ * H_; i += 256) {
    const int cc = i / H_, l = i % H_;
    float s = 0.f;
    for (int j = 0; j < k; ++j) {
      const int ll = l + j - pad;
      if (ll >= 0 && ll < H_) s += sin_[cc * H_ + ll] * wt[cc * k + j];
    }
    sconv[i] = s;
    lsum += s; lsq += s * s;
  }
  #pragma unroll
  for (int m = 32; m >= 1; m >>= 1) { lsum += __shfl_xor(lsum, m); lsq += __shfl_xor(lsq, m); }
  const int wid = t >> 6;
  if ((t & 63) == 0) { redS[wid] = lsum; redQ[wid] = lsq; }
  __syncthreads();
  if (t == 0) {
    const float S = redS[0] + redS[1] + redS[2] + redS[3];
    const float Q = redQ[0] + redQ[1] + redQ[2] + redQ[3];
    const float mu = S / (float)(CG_ * H_);
    const float var = Q / (float)(CG_ * H_) - mu * mu;
    sMu = mu; sRs = rsqrtf(var + EPS_);
  }
  __syncthreads();
  const float mu = sMu, rs = sRs;
  for (int i = t; i < CG_ * H_; i += 256) {
    const int cc = i / H_;
    const int c = g * CG_ + cc;
    const float v = (sconv[i] - mu) * rs * gw[c] + gb[c];
    buf[base + i] = sig_(v);
  }
}

// ---------------- K3: 8x8 block pool of x*Ah*Aw -> xp (B,C,49) ----------------
__global__ __launch_bounds__(448) void k3_pool(const float* __restrict__ x,
    const float* __restrict__ Ah, const float* __restrict__ Aw,
    float* __restrict__ xp) {
  __shared__ float ah[H_];
  __shared__ float aw[W_];
  __shared__ float part[H_ * P_];   // [h][pw], 392
  const int bc = blockIdx.x, t = threadIdx.x;
  if (t < H_) ah[t] = Ah[(size_t)bc * H_ + t];
  else if (t >= 64 && t < 64 + W_) aw[t - 64] = Aw[(size_t)bc * W_ + (t - 64)];
  __syncthreads();
  const f4v* xx = (const f4v*)(x + (size_t)bc * PLANE_);
  if (t < H_ * P_) {   // 392 <= 448: single pass
    const int h = t / P_, pw = t % P_;
    const f4v a = xx[h * 14 + 2 * pw];       // max 55*14+12 = 782 < 784
    const f4v b = xx[h * 14 + 2 * pw + 1];
    const int w0 = 8 * pw;
    float s = a.x * aw[w0]     + a.y * aw[w0 + 1] + a.z * aw[w0 + 2] + a.w * aw[w0 + 3]
            + b.x * aw[w0 + 4] + b.y * aw[w0 + 5] + b.z * aw[w0 + 6] + b.w * aw[w0 + 7];
    part[t] = s * ah[h];
  }
  __syncthreads();
  if (t < N_) {
    const int ph = t / P_, pw = t % P_;
    float s = 0.f;
    #pragma unroll
    for (int r = 0; r < 8; ++r) s += part[(8 * ph + r) * P_ + pw];
    xp[(size_t)bc * N_ + t] = s * (1.0f / 64.0f);
  }
}

// ------- K4: GN(1 group) + channel attention -> Mc (B,C). grid (8, B_), block 256 -------
__global__ __launch_bounds__(256) void k4_attn(const float* __restrict__ xp,
    const float* __restrict__ gw, const float* __restrict__ gb,
    const float* __restrict__ wq, const float* __restrict__ wk, const float* __restrict__ wv,
    float* __restrict__ Mc) {
  __shared__ float xn[C_ * N_];   // 12544 floats
  __shared__ float vbar[C_];
  __shared__ float swk[C_];
  __shared__ float redS[4], redQ[4];
  __shared__ float sMu, sRs;
  const int chunk = blockIdx.x, b = blockIdx.y, t = threadIdx.x;
  const float* src = xp + (size_t)b * C_ * N_;

  float lsum = 0.f, lsq = 0.f;
  for (int i = t; i < C_ * N_; i += 256) {
    const float v = src[i];
    xn[i] = v; lsum += v; lsq += v * v;
  }
  swk[t] = wk[t];
  #pragma unroll
  for (int m = 32; m >= 1; m >>= 1) { lsum += __shfl_xor(lsum, m); lsq += __shfl_xor(lsq, m); }
  const int wid = t >> 6;
  if ((t & 63) == 0) { redS[wid] = lsum; redQ[wid] = lsq; }
  __syncthreads();
  if (t == 0) {
    const float S = redS[0] + redS[1] + redS[2] + redS[3];
    const float Q = redQ[0] + redQ[1] + redQ[2] + redQ[3];
    const float mu = S / (float)(C_ * N_);
    const float var = Q / (float)(C_ * N_) - mu * mu;
    sMu = mu; sRs = rsqrtf(var + EPS_);
  }
  __syncthreads();
  const float mu = sMu, rs = sRs;
  for (int i = t; i < C_ * N_; i += 256) {
    const int c = i / N_;
    xn[i] = (xn[i] - mu) * rs * gw[c] + gb[c];
  }
  __syncthreads();
  {   // vbar[d] = wv[d] * mean_n xn[d,n]
    float s = 0.f;
    #pragma unroll
    for (int n = 0; n < N_; ++n) s += xn[t * N_ + n];
    vbar[t] = wv[t] * s * (1.0f / N_);
  }
  __syncthreads();

  const int r = t >> 3, q8 = t & 7;     // 32 rows x 8 collaborators
  const int c = chunk * 32 + r;
  const float qscale = wq[c] * (1.0f / 7.0f);   // 1/sqrt(49)

  float qrow[N_];
  #pragma unroll
  for (int n = 0; n < N_; ++n) qrow[n] = xn[c * N_ + n];

  float s[32];
  #pragma unroll
  for (int dd = 0; dd < 32; ++dd) {
    const int d = q8 + 8 * dd;          // interleaved -> conflict-free LDS banks
    const float* kb = &xn[d * N_];
    float dot = 0.f;
    #pragma unroll
    for (int n = 0; n < N_; ++n) dot += qrow[n] * kb[n];
    s[dd] = dot * qscale * swk[d];
  }
  float mx = -INFINITY;
  #pragma unroll
  for (int dd = 0; dd < 32; ++dd) mx = fmaxf(mx, s[dd]);
  #pragma unroll
  for (int msk = 1; msk < 8; msk <<= 1) mx = fmaxf(mx, __shfl_xor(mx, msk));
  float esum = 0.f, acc = 0.f;
  #pragma unroll
  for (int dd = 0; dd < 32; ++dd) {
    const float e = expf(s[dd] - mx);
    esum += e;
    acc += e * vbar[q8 + 8 * dd];
  }
  #pragma unroll
  for (int msk = 1; msk < 8; msk <<= 1) { esum += __shfl_xor(esum, msk); acc += __shfl_xor(acc, msk); }
  if (q8 == 0) Mc[(size_t)b * C_ + c] = sig_(acc / esum);
}

// ---------------- K5: out = x * Ah * Aw * Mc (non-temporal out stores) ----------------
__global__ __launch_bounds__(256) void k5_out(const float* __restrict__ x,
    const float* __restrict__ Ah, const float* __restrict__ Aw,
    const float* __restrict__ Mc, float* __restrict__ out) {
  __shared__ float ah[H_];
  __shared__ __align__(16) float aw[W_];
  __shared__ float smc;
  const int bc = blockIdx.x, t = threadIdx.x;
  if (t < H_) ah[t] = Ah[(size_t)bc * H_ + t];
  else if (t >= 64 && t < 64 + W_) aw[t - 64] = Aw[(size_t)bc * W_ + (t - 64)];
  if (t == 128) smc = Mc[bc];
  __syncthreads();
  const f4v* xx = (const f4v*)(x + (size_t)bc * PLANE_);
  f4v* oo = (f4v*)(out + (size_t)bc * PLANE_);
  const float mc = smc;
  for (int i = t; i < PLANE_ / 4; i += 256) {   // 784 f4v
    const int h = i / 14, w4 = i % 14;
    f4v v = xx[i];
    const float a = ah[h] * mc;
    const f4v awv = ((const f4v*)aw)[w4];
    v = v * (a * awv);
    __builtin_nontemporal_store(v, &oo[i]);
  }
}

extern "C" void kernel_launch(void* const* d_in, const int* in_sizes, int n_in,
                              void* d_out, int out_size, void* d_ws, size_t ws_size,
                              hipStream_t stream) {
  // setup_inputs() dict order: x, dwh0, dww0, dwh1, dww1, dwh2, dww2, dwh3, dww3,
  // gnh_w, gnh_b, gnw_w, gnw_b, gn1_w, gn1_b, wq, wk, wv
  const float* x     = (const float*)d_in[0];
  const float* dwh0  = (const float*)d_in[1];
  const float* dww0  = (const float*)d_in[2];
  const float* dwh1  = (const float*)d_in[3];
  const float* dww1  = (const float*)d_in[4];
  const float* dwh2  = (const float*)d_in[5];
  const float* dww2  = (const float*)d_in[6];
  const float* dwh3  = (const float*)d_in[7];
  const float* dww3  = (const float*)d_in[8];
  const float* gnh_w = (const float*)d_in[9];
  const float* gnh_b = (const float*)d_in[10];
  const float* gnw_w = (const float*)d_in[11];
  const float* gnw_b = (const float*)d_in[12];
  const float* gn1_w = (const float*)d_in[13];
  const float* gn1_b = (const float*)d_in[14];
  const float* wq    = (const float*)d_in[15];
  const float* wk    = (const float*)d_in[16];
  const float* wv    = (const float*)d_in[17];
  float* out = (float*)d_out;

  float* ws   = (float*)d_ws;
  float* bufh = ws;                                   // (B,C,56): x_h then Ah in-place
  float* bufw = bufh + (size_t)B_ * C_ * H_;          // (B,C,56): x_w then Aw in-place
  float* xp   = bufw + (size_t)B_ * C_ * W_;          // (B,C,49)
  float* Mc   = xp + (size_t)B_ * C_ * N_;            // (B,C)

  const int nbc = B_ * C_;
  k1_means<<<nbc, 256, 0, stream>>>(x, bufh, bufw);
  k2_convgn<<<dim3(NG_, B_, 2), 256, 0, stream>>>(bufh, bufw,
      dwh0, dwh1, dwh2, dwh3, dww0, dww1, dww2, dww3,
      gnh_w, gnh_b, gnw_w, gnw_b);
  k3_pool<<<nbc, 448, 0, stream>>>(x, bufh, bufw, xp);
  k4_attn<<<dim3(8, B_), 256, 0, stream>>>(xp, gn1_w, gn1_b, wq, wk, wv, Mc);
  k5_out<<<nbc, 256, 0, stream>>>(x, bufh, bufw, Mc, out);
}